// Round 7
// baseline (199.435 us; speedup 1.0000x reference)
//
#include <hip/hip_runtime.h>

namespace {

typedef float v4f __attribute__((ext_vector_type(4)));
typedef _Float16 half4 __attribute__((ext_vector_type(4)));
typedef __fp16 fp16x2 __attribute__((ext_vector_type(2)));
typedef unsigned int uint32;

constexpr int   kB     = 32768;
constexpr int   kT     = 50;
constexpr float kDT    = 0.01f;
constexpr float kGamma = 0.1f;
constexpr float kSigma = 0.2f;
constexpr float kTau   = 0.5f;
constexpr float kA     = 2.8853900817779268f;   // 2*log2(e)

// 25 MFMA A-fragments (v_mfma_f32_16x16x16_f16; lane holds A[m][k], m=lane&15,
// k=(lane>>4)*4+j). ACTIVATION-FOLDED as before.
// 0 y0L1  1 y0L2  2 y0L3  3 L1z(x)  4 L1p(x)  5 L2z  6 L2p  7 L3z  8 L3p
// 9 Arow 10 Brow 11 Crow 12 Drow 13 Acol 14 Ccol 15 Bcol 16 Dcol
// RECURRENCE-EXPANSION products (W1x = kA-scaled x-rows of W1):
// 17 PAz=dt*W1zx*A  18 PCz=W1zx*C  19 PBz=dt*W1zx*B  20 PDz=W1zx*D
// 21 PAp=dt*W1px*A  22 PCp=W1px*C  23 PBp=dt*W1px*B  24 PDp=W1px*D
constexpr int kNFrag      = 25;
constexpr int kFragDwords = kNFrag * 128;
// bias arrays (16 f32 each):
// 0 cy1 1 cy2 2 cy3 3 c2z 4 c2p 5 c3z 6 c3p 7 vtz 8 vbz 9 vtp 10 vbp
// 11 w1sz=kA*rowsum(W1zx) 12 w1sp
constexpr int kBiasFloats = 13 * 16;

__device__ __forceinline__ float fexp2(float x) {
#if __has_builtin(__builtin_amdgcn_exp2f)
  return __builtin_amdgcn_exp2f(x);
#else
  return exp2f(x);
#endif
}

__device__ __forceinline__ float fact(float x) {   // rcp(exp2(x)+1)
  return __builtin_amdgcn_rcpf(fexp2(x) + 1.0f);
}

__device__ __forceinline__ v4f act4(v4f a) {
  v4f r;
  r[0] = fact(a[0]); r[1] = fact(a[1]);
  r[2] = fact(a[2]); r[3] = fact(a[3]);
  return r;
}

__device__ __forceinline__ uint32 pk2rtn(float a, float b) {  // round-nearest
  union { _Float16 h[2]; uint32 u; } z;
  z.h[0] = (_Float16)a; z.h[1] = (_Float16)b;
  return z.u;
}

// ---------------- prep: 26 blocks, one fragment (or bias set) each ---------
__global__ __launch_bounds__(64) void prep_kernel(
    const float* __restrict__ A,   const float* __restrict__ Bm,
    const float* __restrict__ Cm,  const float* __restrict__ Dm,
    const float* __restrict__ pW1, const float* __restrict__ pb1,
    const float* __restrict__ pW2, const float* __restrict__ pb2,
    const float* __restrict__ pW3, const float* __restrict__ pb3,
    const float* __restrict__ zW1, const float* __restrict__ zb1,
    const float* __restrict__ zW2, const float* __restrict__ zb2,
    const float* __restrict__ zW3, const float* __restrict__ zb3,
    const float* __restrict__ yW1, const float* __restrict__ yb1,
    const float* __restrict__ yW2, const float* __restrict__ yb2,
    const float* __restrict__ yW3, const float* __restrict__ yb3,
    uint32* __restrict__ ws)
{
  const int tid = threadIdx.x;
  const int blk = blockIdx.x;

  auto sum10 = [](const float* W, int stride, int mm) {
    float s = 0.f;
#pragma unroll
    for (int j = 0; j < 10; ++j) s += W[j * stride + mm];
    return s;
  };

  if (blk < kNFrag) {
    const int m = tid & 15, q = tid >> 4;
    const int p = blk;

    // composite: kA*scale * sum_i W1[(i+1)*10+m] * M[i*ncol+k]
    auto comp = [&](const float* W1, const float* M, int ncol, int k,
                    float scale) -> float {
      if (m >= 10 || k >= ncol) return 0.f;
      float s = 0.f;
#pragma unroll
      for (int i = 0; i < 16; ++i) s += W1[(i + 1) * 10 + m] * M[i * ncol + k];
      return kA * scale * s;
    };

    auto wv = [&](int k) -> float {
      switch (p) {
        case 0:  return (m < 10) ? kA * yW1[k * 10 + m] : 0.f;
        case 1:  return (m < 10 && k < 10) ? -2.f * kA * yW2[k * 10 + m] : 0.f;
        case 2:  return (k < 10) ? -2.f * yW3[k * 16 + m] : 0.f;
        case 3:  return (m < 10) ? kA * zW1[(k + 1) * 10 + m] : 0.f;
        case 4:  return (m < 10) ? kA * pW1[(k + 1) * 10 + m] : 0.f;
        case 5:  return (m < 10 && k < 10) ? -2.f * kA * zW2[k * 10 + m] : 0.f;
        case 6:  return (m < 10 && k < 10) ? -2.f * kA * pW2[k * 10 + m] : 0.f;
        case 7:  return (k < 10) ? -2.f * zW3[k * 16 + m] : 0.f;
        case 8:  return (m < 8 && k < 10) ? -2.f * pW3[k * 8 + m] : 0.f;
        case 9:  return A[m * 16 + k];
        case 10: return (k < 8) ? Bm[m * 8 + k] : 0.f;
        case 11: return Cm[m * 16 + k];
        case 12: return (k < 8) ? Dm[m * 8 + k] : 0.f;
        case 13: return A[k * 16 + m];
        case 14: return Cm[k * 16 + m];
        case 15: return (m < 8) ? Bm[k * 8 + m] : 0.f;
        case 16: return (m < 8) ? Dm[k * 8 + m] : 0.f;
        case 17: return comp(zW1, A,  16, k, kDT);
        case 18: return comp(zW1, Cm, 16, k, 1.f);
        case 19: return comp(zW1, Bm,  8, k, kDT);
        case 20: return comp(zW1, Dm,  8, k, 1.f);
        case 21: return comp(pW1, A,  16, k, kDT);
        case 22: return comp(pW1, Cm, 16, k, 1.f);
        case 23: return comp(pW1, Bm,  8, k, kDT);
        case 24: return comp(pW1, Dm,  8, k, 1.f);
      }
      return 0.f;
    };

    const int k0 = 4 * q;
    ws[p * 128 + tid * 2]     = pk2rtn(wv(k0),     wv(k0 + 1));
    ws[p * 128 + tid * 2 + 1] = pk2rtn(wv(k0 + 2), wv(k0 + 3));
  } else {
    float* bsf = (float*)(ws + kFragDwords);
    auto sumx = [&](const float* W1, int mm) {   // kA * sum of x-rows
      float s = 0.f;
#pragma unroll
      for (int i = 0; i < 16; ++i) s += W1[(i + 1) * 10 + mm];
      return kA * s;
    };
    auto bval = [&](int a, int mm) -> float {
      const bool m10 = mm < 10;
      switch (a) {
        case 0:  return m10 ? kA * yb1[mm] : 0.f;
        case 1:  return m10 ? kA * (yb2[mm] + sum10(yW2, 10, mm)) : 0.f;
        case 2:  return yb3[mm] + sum10(yW3, 16, mm);
        case 3:  return m10 ? kA * (zb2[mm] + sum10(zW2, 10, mm)) : 0.f;
        case 4:  return m10 ? kA * (pb2[mm] + sum10(pW2, 10, mm)) : 0.f;
        case 5:  return zb3[mm] + sum10(zW3, 16, mm);
        case 6:  return (mm < 8) ? pb3[mm] + sum10(pW3, 8, mm) : 0.f;
        case 7:  return m10 ? kA * zW1[mm] : 0.f;   // zW1 row 0 = t-row
        case 8:  return m10 ? kA * zb1[mm] : 0.f;
        case 9:  return m10 ? kA * pW1[mm] : 0.f;
        case 10: return m10 ? kA * pb1[mm] : 0.f;
        case 11: return m10 ? sumx(zW1, mm) : 0.f;
        case 12: return m10 ? sumx(pW1, mm) : 0.f;
      }
      return 0.f;
    };
    for (int j = tid; j < kBiasFloats; j += 64) {
      bsf[j] = bval(j >> 4, j & 15);
    }
  }
}

// --------- main: recurrence-expanded K=16 MFMA chain (short critical path) --
__global__ __launch_bounds__(64)
__attribute__((amdgpu_waves_per_eu(2, 2)))
void bsde_kernel(const float* __restrict__ dw, const float* __restrict__ X0,
                 const uint32* __restrict__ wsu, float* __restrict__ out)
{
  const int lane = threadIdx.x;
  const int col  = lane & 15;
  const int quad = lane >> 4;
  const int e    = blockIdx.x * 16 + col;
  const int bq   = quad * 4;

  half4 af[kNFrag];
#pragma unroll
  for (int p = 0; p < kNFrag; ++p) {
    union { uint2 u; half4 h; } z;
    z.u = *(const uint2*)(wsu + p * 128 + lane * 2);
    af[p] = z.h;
  }

  const float* bsf = (const float*)(wsu + kFragDwords);
  const v4f c2z  = *(const v4f*)&bsf[3 * 16 + bq];
  const v4f c2p  = *(const v4f*)&bsf[4 * 16 + bq];
  const v4f c3z  = *(const v4f*)&bsf[5 * 16 + bq];
  const v4f c3p  = *(const v4f*)&bsf[6 * 16 + bq];
  const v4f vtz  = *(const v4f*)&bsf[7 * 16 + bq];
  const v4f vbz  = *(const v4f*)&bsf[8 * 16 + bq];
  const v4f vtp  = *(const v4f*)&bsf[9 * 16 + bq];
  const v4f vbp  = *(const v4f*)&bsf[10 * 16 + bq];
  const v4f w1sz = *(const v4f*)&bsf[11 * 16 + bq];
  const v4f w1sp = *(const v4f*)&bsf[12 * 16 + bq];

  auto pk4 = [](v4f a) -> half4 {
    union { fp16x2 p[2]; half4 h; } z;
    z.p[0] = __builtin_amdgcn_cvt_pkrtz(a[0], a[1]);
    z.p[1] = __builtin_amdgcn_cvt_pkrtz(a[2], a[3]);
    return z.h;
  };
  auto mm4 = [](half4 a, half4 b, v4f c) -> v4f {
    return __builtin_amdgcn_mfma_f32_16x16x16f16(a, b, c, 0, 0, 0);
  };

  const v4f gam4  = {kGamma, kGamma, kGamma, kGamma};
  const v4f sig4  = {kSigma, kSigma, kSigma, kSigma};
  const v4f zero4 = {0.f, 0.f, 0.f, 0.f};

  // ---- init: X0 load, Y0 MLP, L1 pre-acts at t=0 ----
  v4f x4 = *(const v4f*)&X0[e * 16 + bq];
  half4 xB = pk4(x4);
  v4f y4;
  {
    const v4f cy1 = *(const v4f*)&bsf[0 * 16 + bq];
    const v4f cy2 = *(const v4f*)&bsf[1 * 16 + bq];
    const v4f cy3 = *(const v4f*)&bsf[2 * 16 + bq];
    v4f h = mm4(af[0], xB, cy1);
    v4f g = mm4(af[1], pk4(act4(h)), cy2);
    y4    = mm4(af[2], pk4(act4(g)), cy3);
  }
  v4f hzp = mm4(af[3], xB, vbz);     // L1 pre-act at t=0 (tv=0)
  v4f hpp = mm4(af[4], xB, vbp);

  float dwv = dw[e];
  v4f xs0;
#pragma unroll
  for (int r = 0; r < 4; ++r) xs0[r] = x4[r] * dwv;
  half4 xDB = pk4(xs0);

  float lcp = 0.0f;

  // ------------------------------- time loop -------------------------------
#pragma unroll 1
  for (int t = 0; t < kT; ++t) {
    const float dwn = (t < kT - 1) ? dw[(t + 1) * kB + e] : 0.0f;
    const float tvn = (float)(t + 1) * kDT;
    const float wt  = (t == 0 || t == kT - 1) ? 1.0f : 2.0f;

    half4 yB = pk4(y4);

    // ---- EARLY (x/y only; hides under critical chain) ----
    v4f dx1 = mm4(af[9],  xB, gam4);
    v4f fx1 = mm4(af[11], xB, sig4);
    v4f dy1 = mm4(af[13], yB, x4);      // +X folded into C
    v4f dh1 = mm4(af[15], yB, zero4);

    const float gs = kDT * kGamma + dwv * kSigma;
    v4f Cz, Cp;
#pragma unroll
    for (int r = 0; r < 4; ++r) {
      Cz[r] = vbz[r] + tvn * vtz[r] + gs * w1sz[r];
      Cp[r] = vbp[r] + tvn * vtp[r] + gs * w1sp[r];
    }
    // Ez = W1zx*x + dt*PAz*x + dwv*PCz*x + bias(t+1)+t-row+gam/sig terms
    v4f Ez = mm4(af[18], xDB, mm4(af[17], xB, mm4(af[3], xB, Cz)));
    v4f Ep = mm4(af[22], xDB, mm4(af[21], xB, mm4(af[4], xB, Cp)));

    // ---- CRITICAL chain: act(L1) -> L2 -> act -> L3 ----
    v4f gz = mm4(af[5], pk4(act4(hzp)), c2z);
    v4f gp = mm4(af[6], pk4(act4(hpp)), c2p);
    v4f zv = mm4(af[7], pk4(act4(gz)), c3z);
    v4f uu = mm4(af[8], pk4(act4(gp)), c3p);   // rows >= 8 exactly 0

    half4 zB = pk4(zv);
    half4 uB = pk4(uu);

    // ---- LATE (on u/z) ----
    v4f dx  = mm4(af[10], uB, dx1);    // x@A^T + u@B^T + gamma
    v4f fx  = mm4(af[12], uB, fx1);    // x@C^T + u@D^T + sigma
    v4f dy  = mm4(af[14], zB, dy1);    // Y@A + Z@C + X
    v4f dh  = mm4(af[16], zB, dh1);    // Y@B + Z@D
    v4f l1z = mm4(af[19], uB, Ez);     // + dt*PBz*u
    v4f l2z = mm4(af[20], uB, zero4);  //   PDz*u
    v4f l1p = mm4(af[23], uB, Ep);
    v4f l2p = mm4(af[24], uB, zero4);

    // h(t+1) = Ez + dt*PBz*u + dwv*PDz*u  (1 FMA closes the recurrence)
#pragma unroll
    for (int r = 0; r < 4; ++r) {
      hzp[r] = l1z[r] + dwv * l2z[r];
      hpp[r] = l1p[r] + dwv * l2p[r];
    }

    float ss = 0.0f;
    v4f Xn, Yn;
#pragma unroll
    for (int r = 0; r < 4; ++r) {
      Xn[r] = x4[r] + kDT * dx[r] + dwv * fx[r];
      Yn[r] = y4[r] - kDT * dy[r] + dwv * zv[r];
      float d = dh[r] + uu[r];
      ss += d * d;
    }
    lcp += (0.5f * kDT * kTau * kTau) * wt * ss;
    x4 = Xn; y4 = Yn;
    xB = pk4(x4);
    v4f xs;
#pragma unroll
    for (int r = 0; r < 4; ++r) xs[r] = x4[r] * dwn;
    xDB = pk4(xs);
    dwv = dwn;
  }

  // ---- losses ----
  float bp = 0.0f;
#pragma unroll
  for (int r = 0; r < 4; ++r) { float d = y4[r] - x4[r]; bp += d * d; }

#pragma unroll
  for (int s = 32; s > 0; s >>= 1) {
    bp  += __shfl_down(bp,  s, 64);
    lcp += __shfl_down(lcp, s, 64);
  }
  if (lane == 0) {
    atomicAdd(&out[0], bp  * (1.0f / (float)kB));
    atomicAdd(&out[1], lcp * (1.0f / (float)kB));
  }
}

} // namespace

extern "C" void kernel_launch(void* const* d_in, const int* in_sizes, int n_in,
                              void* d_out, int out_size, void* d_ws, size_t ws_size,
                              hipStream_t stream) {
  (void)in_sizes; (void)n_in; (void)ws_size; (void)out_size;

  const float* dw  = (const float*)d_in[0];
  const float* X0  = (const float*)d_in[1];
  const float* A   = (const float*)d_in[2];
  const float* Bm  = (const float*)d_in[3];
  const float* Cm  = (const float*)d_in[4];
  const float* Dm  = (const float*)d_in[5];
  const float* pW1 = (const float*)d_in[6];
  const float* pb1 = (const float*)d_in[7];
  const float* pW2 = (const float*)d_in[8];
  const float* pb2 = (const float*)d_in[9];
  const float* pW3 = (const float*)d_in[10];
  const float* pb3 = (const float*)d_in[11];
  const float* zW1 = (const float*)d_in[12];
  const float* zb1 = (const float*)d_in[13];
  const float* zW2 = (const float*)d_in[14];
  const float* zb2 = (const float*)d_in[15];
  const float* zW3 = (const float*)d_in[16];
  const float* zb3 = (const float*)d_in[17];
  const float* yW1 = (const float*)d_in[18];
  const float* yb1 = (const float*)d_in[19];
  const float* yW2 = (const float*)d_in[20];
  const float* yb2 = (const float*)d_in[21];
  const float* yW3 = (const float*)d_in[22];
  const float* yb3 = (const float*)d_in[23];
  float* out = (float*)d_out;
  unsigned int* ws = (unsigned int*)d_ws;

  (void)hipMemsetAsync(out, 0, 2 * sizeof(float), stream);

  prep_kernel<<<26, 64, 0, stream>>>(
      A, Bm, Cm, Dm,
      pW1, pb1, pW2, pb2, pW3, pb3,
      zW1, zb1, zW2, zb2, zW3, zb3,
      yW1, yb1, yW2, yb2, yW3, yb3, ws);

  bsde_kernel<<<kB / 16, 64, 0, stream>>>(dw, X0, ws, out);
}

// Round 8
// 185.434 us; speedup vs baseline: 1.0755x; 1.0755x over previous
//
#include <hip/hip_runtime.h>

namespace {

typedef float v4f __attribute__((ext_vector_type(4)));
typedef _Float16 half4 __attribute__((ext_vector_type(4)));
typedef __fp16 fp16x2 __attribute__((ext_vector_type(2)));
typedef unsigned int uint32;

constexpr int   kB     = 32768;
constexpr int   kT     = 50;
constexpr float kDT    = 0.01f;
constexpr float kGamma = 0.1f;
constexpr float kSigma = 0.2f;
constexpr float kTau   = 0.5f;
constexpr float kA     = 2.8853900817779268f;   // 2*log2(e)

// 17 MFMA A-fragments (v_mfma_f32_16x16x16_f16; lane holds A[m][k], m=lane&15,
// k=(lane>>4)*4+j). ACTIVATION-FOLDED: act(v)=rcp(exp2(v)+1); tanh=1-2r folded
// into next layer (W'=-2W, b'=b+sumW); act-feeding layers pre-scaled by kA.
// 0 y0L1  1 y0L2  2 y0L3  3 L1z(x)  4 L1p(x)  5 L2z  6 L2p  7 L3z  8 L3p
// 9 Arow 10 Brow 11 Crow 12 Drow 13 Acol 14 Ccol 15 Bcol 16 Dcol
constexpr int kNFrag      = 17;
constexpr int kFragDwords = kNFrag * 128;
// bias arrays (16 f32 each):
// 0 cy1 1 cy2 2 cy3 3 c2z 4 c2p 5 c3z 6 c3p 7 vtz 8 vbz 9 vtp 10 vbp
constexpr int kBiasFloats = 11 * 16;

__device__ __forceinline__ float fexp2(float x) {
#if __has_builtin(__builtin_amdgcn_exp2f)
  return __builtin_amdgcn_exp2f(x);
#else
  return exp2f(x);
#endif
}

__device__ __forceinline__ float fact(float x) {   // rcp(exp2(x)+1)
  return __builtin_amdgcn_rcpf(fexp2(x) + 1.0f);
}

__device__ __forceinline__ v4f act4(v4f a) {
  v4f r;
  r[0] = fact(a[0]); r[1] = fact(a[1]);
  r[2] = fact(a[2]); r[3] = fact(a[3]);
  return r;
}

__device__ __forceinline__ uint32 pk2rtn(float a, float b) {  // round-nearest
  union { _Float16 h[2]; uint32 u; } z;
  z.h[0] = (_Float16)a; z.h[1] = (_Float16)b;
  return z.u;
}

// ---------------- prep: 18 blocks, one fragment (or bias set) each ---------
__global__ __launch_bounds__(64) void prep_kernel(
    const float* __restrict__ A,   const float* __restrict__ Bm,
    const float* __restrict__ Cm,  const float* __restrict__ Dm,
    const float* __restrict__ pW1, const float* __restrict__ pb1,
    const float* __restrict__ pW2, const float* __restrict__ pb2,
    const float* __restrict__ pW3, const float* __restrict__ pb3,
    const float* __restrict__ zW1, const float* __restrict__ zb1,
    const float* __restrict__ zW2, const float* __restrict__ zb2,
    const float* __restrict__ zW3, const float* __restrict__ zb3,
    const float* __restrict__ yW1, const float* __restrict__ yb1,
    const float* __restrict__ yW2, const float* __restrict__ yb2,
    const float* __restrict__ yW3, const float* __restrict__ yb3,
    uint32* __restrict__ ws)
{
  const int tid = threadIdx.x;
  const int blk = blockIdx.x;

  auto sum10 = [](const float* W, int stride, int mm) {
    float s = 0.f;
#pragma unroll
    for (int j = 0; j < 10; ++j) s += W[j * stride + mm];
    return s;
  };

  if (blk < kNFrag) {
    const int m = tid & 15, q = tid >> 4;
    const int p = blk;

    auto wv = [&](int k) -> float {
      switch (p) {
        case 0:  return (m < 10) ? kA * yW1[k * 10 + m] : 0.f;
        case 1:  return (m < 10 && k < 10) ? -2.f * kA * yW2[k * 10 + m] : 0.f;
        case 2:  return (k < 10) ? -2.f * yW3[k * 16 + m] : 0.f;
        case 3:  return (m < 10) ? kA * zW1[(k + 1) * 10 + m] : 0.f;
        case 4:  return (m < 10) ? kA * pW1[(k + 1) * 10 + m] : 0.f;
        case 5:  return (m < 10 && k < 10) ? -2.f * kA * zW2[k * 10 + m] : 0.f;
        case 6:  return (m < 10 && k < 10) ? -2.f * kA * pW2[k * 10 + m] : 0.f;
        case 7:  return (k < 10) ? -2.f * zW3[k * 16 + m] : 0.f;
        case 8:  return (m < 8 && k < 10) ? -2.f * pW3[k * 8 + m] : 0.f;
        case 9:  return A[m * 16 + k];                      // dx: x @ A^T
        case 10: return (k < 8) ? Bm[m * 8 + k] : 0.f;      // dx: u @ B^T
        case 11: return Cm[m * 16 + k];                     // fx: x @ C^T
        case 12: return (k < 8) ? Dm[m * 8 + k] : 0.f;      // fx: u @ D^T
        case 13: return A[k * 16 + m];                      // dy: Y @ A
        case 14: return Cm[k * 16 + m];                     // dy: Z @ C
        case 15: return (m < 8) ? Bm[k * 8 + m] : 0.f;      // dh: Y @ B
        case 16: return (m < 8) ? Dm[k * 8 + m] : 0.f;      // dh: Z @ D
      }
      return 0.f;
    };

    const int k0 = 4 * q;
    ws[p * 128 + tid * 2]     = pk2rtn(wv(k0),     wv(k0 + 1));
    ws[p * 128 + tid * 2 + 1] = pk2rtn(wv(k0 + 2), wv(k0 + 3));
  } else {
    float* bsf = (float*)(ws + kFragDwords);
    auto bval = [&](int a, int mm) -> float {
      const bool m10 = mm < 10;
      switch (a) {
        case 0:  return m10 ? kA * yb1[mm] : 0.f;
        case 1:  return m10 ? kA * (yb2[mm] + sum10(yW2, 10, mm)) : 0.f;
        case 2:  return yb3[mm] + sum10(yW3, 16, mm);
        case 3:  return m10 ? kA * (zb2[mm] + sum10(zW2, 10, mm)) : 0.f;
        case 4:  return m10 ? kA * (pb2[mm] + sum10(pW2, 10, mm)) : 0.f;
        case 5:  return zb3[mm] + sum10(zW3, 16, mm);
        case 6:  return (mm < 8) ? pb3[mm] + sum10(pW3, 8, mm) : 0.f;
        case 7:  return m10 ? kA * zW1[mm] : 0.f;   // zW1 row 0 = t-row
        case 8:  return m10 ? kA * zb1[mm] : 0.f;
        case 9:  return m10 ? kA * pW1[mm] : 0.f;
        case 10: return m10 ? kA * pb1[mm] : 0.f;
      }
      return 0.f;
    };
    for (int j = tid; j < kBiasFloats; j += 64) {
      bsf[j] = bval(j >> 4, j & 15);
    }
  }
}

// --- main: 2-wave cooperative WG. wave1 = X/phi-net, wave0 = Y/Z-net+loss ---
// Exchange per step via LDS (f32, bit-exact): wave1 -> {u, Xn}; 1 barrier.
__global__ __launch_bounds__(128)
__attribute__((amdgpu_waves_per_eu(2, 4)))
void bsde_kernel(const float* __restrict__ dw, const float* __restrict__ X0,
                 const uint32* __restrict__ wsu, float* __restrict__ out)
{
  const int tid  = threadIdx.x;
  const int w    = tid >> 6;          // 0: Y/Z-wave, 1: X/phi-wave
  const int lane = tid & 63;
  const int col  = lane & 15;
  const int quad = lane >> 4;
  const int e    = blockIdx.x * 16 + col;
  const int bq   = quad * 4;

  __shared__ float sx[2][64][4];      // x4(t+1) from wave1
  __shared__ float su[2][64][4];      // u(t)    from wave1

  auto ldfrag = [&](int p) -> half4 {
    union { uint2 u; half4 h; } z;
    z.u = *(const uint2*)(wsu + p * 128 + lane * 2);
    return z.h;
  };
  const float* bsf = (const float*)(wsu + kFragDwords);

  // Per-wave fragment/bias selection (wave-uniform indices).
  const half4 aL1 = ldfrag(w ? 4 : 3);     // L1p / L1z
  const half4 aL2 = ldfrag(w ? 6 : 5);     // L2p / L2z
  const half4 aL3 = ldfrag(w ? 8 : 7);     // L3p / L3z
  const half4 aE0 = ldfrag(w ? 9 : 13);    // Arow / Acol
  const half4 aE1 = ldfrag(w ? 10 : 14);   // Brow / Ccol
  const half4 aE2 = ldfrag(w ? 11 : 15);   // Crow / Bcol
  const half4 aE3 = ldfrag(w ? 12 : 16);   // Drow / Dcol
  const v4f c2 = *(const v4f*)&bsf[(w ? 4 : 3) * 16 + bq];
  const v4f c3 = *(const v4f*)&bsf[(w ? 6 : 5) * 16 + bq];
  const v4f vt = *(const v4f*)&bsf[(w ? 9 : 7) * 16 + bq];
  const v4f vb = *(const v4f*)&bsf[(w ? 10 : 8) * 16 + bq];

  auto pk4 = [](v4f a) -> half4 {
    union { fp16x2 p[2]; half4 h; } z;
    z.p[0] = __builtin_amdgcn_cvt_pkrtz(a[0], a[1]);
    z.p[1] = __builtin_amdgcn_cvt_pkrtz(a[2], a[3]);
    return z.h;
  };
  auto mm4 = [](half4 a, half4 b, v4f c) -> v4f {
    return __builtin_amdgcn_mfma_f32_16x16x16f16(a, b, c, 0, 0, 0);
  };

  const v4f gam4  = {kGamma, kGamma, kGamma, kGamma};
  const v4f sig4  = {kSigma, kSigma, kSigma, kSigma};
  const v4f zero4 = {0.f, 0.f, 0.f, 0.f};

  // ---- init ----
  v4f x4 = *(const v4f*)&X0[e * 16 + bq];
  half4 xB = pk4(x4);
  v4f y4 = zero4;
  if (w == 0) {   // Y0 MLP (transient fragments)
    const half4 a0 = ldfrag(0), a1 = ldfrag(1), a2 = ldfrag(2);
    const v4f cy1 = *(const v4f*)&bsf[0 * 16 + bq];
    const v4f cy2 = *(const v4f*)&bsf[1 * 16 + bq];
    const v4f cy3 = *(const v4f*)&bsf[2 * 16 + bq];
    v4f h = mm4(a0, xB, cy1);
    v4f g = mm4(a1, pk4(act4(h)), cy2);
    y4    = mm4(a2, pk4(act4(g)), cy3);
  }

  float dwv = dw[e];
  float lcp = 0.0f;
  int buf = 0;

  // ------------------------------- time loop -------------------------------
#pragma unroll 1
  for (int t = 0; t < kT; ++t) {
    const float dwn = (t < kT - 1) ? dw[(t + 1) * kB + e] : 0.0f;
    const float tv  = (float)t * kDT;
    const float wt  = (t == 0 || t == kT - 1) ? 1.0f : 2.0f;

    // L1 C-init carries t-row and bias: c = kA*(t*W_t + b)
    v4f c1;
#pragma unroll
    for (int r = 0; r < 4; ++r) c1[r] = vb[r] + tv * vt[r];

    // own MLP chain: h -> g -> o   (o = u for wave1, z for wave0)
    v4f h = mm4(aL1, xB, c1);
    v4f g = mm4(aL2, pk4(act4(h)), c2);
    v4f o = mm4(aL3, pk4(act4(g)), c3);
    half4 oB = pk4(o);

    half4 yB = pk4(y4);                       // meaningful in wave0 only
    const half4 firstB = w ? xB : yB;
    const v4f cA = w ? gam4 : x4;             // gamma | +X fold
    const v4f cB = w ? sig4 : zero4;

    v4f s1 = mm4(aE0, firstB, cA);            // Arow·x+γ   | Acol·y+X
    v4f p1 = mm4(aE1, oB, s1);                // dx         | dy
    v4f s2 = mm4(aE2, firstB, cB);            // Crow·x+σ   | Bcol·y
    v4f p2 = mm4(aE3, oB, s2);                // fx         | dh

    v4f Xn, Yn;
    if (w) {
      *(v4f*)&su[buf][lane][0] = o;           // u(t), f32 exact
#pragma unroll
      for (int r = 0; r < 4; ++r) Xn[r] = x4[r] + kDT * p1[r] + dwv * p2[r];
      *(v4f*)&sx[buf][lane][0] = Xn;          // x4(t+1), f32 exact
    } else {
#pragma unroll
      for (int r = 0; r < 4; ++r) Yn[r] = y4[r] - kDT * p1[r] + dwv * o[r];
    }

    __syncthreads();

    if (w) {
      x4 = Xn;
      xB = pk4(x4);
    } else {
      const v4f uu = *(const v4f*)&su[buf][lane][0];
      float ss = 0.0f;
#pragma unroll
      for (int r = 0; r < 4; ++r) { float d = p2[r] + uu[r]; ss += d * d; }
      lcp += (0.5f * kDT * kTau * kTau) * wt * ss;
      y4 = Yn;
      x4 = *(const v4f*)&sx[buf][lane][0];
      xB = pk4(x4);
    }
    dwv = dwn;
    buf ^= 1;
  }

  // ---- losses (wave0 only; no barriers below) ----
  if (w == 0) {
    float bp = 0.0f;
#pragma unroll
    for (int r = 0; r < 4; ++r) { float d = y4[r] - x4[r]; bp += d * d; }
#pragma unroll
    for (int s = 32; s > 0; s >>= 1) {
      bp  += __shfl_down(bp,  s, 64);
      lcp += __shfl_down(lcp, s, 64);
    }
    if (lane == 0) {
      atomicAdd(&out[0], bp  * (1.0f / (float)kB));
      atomicAdd(&out[1], lcp * (1.0f / (float)kB));
    }
  }
}

} // namespace

extern "C" void kernel_launch(void* const* d_in, const int* in_sizes, int n_in,
                              void* d_out, int out_size, void* d_ws, size_t ws_size,
                              hipStream_t stream) {
  (void)in_sizes; (void)n_in; (void)ws_size; (void)out_size;

  const float* dw  = (const float*)d_in[0];
  const float* X0  = (const float*)d_in[1];
  const float* A   = (const float*)d_in[2];
  const float* Bm  = (const float*)d_in[3];
  const float* Cm  = (const float*)d_in[4];
  const float* Dm  = (const float*)d_in[5];
  const float* pW1 = (const float*)d_in[6];
  const float* pb1 = (const float*)d_in[7];
  const float* pW2 = (const float*)d_in[8];
  const float* pb2 = (const float*)d_in[9];
  const float* pW3 = (const float*)d_in[10];
  const float* pb3 = (const float*)d_in[11];
  const float* zW1 = (const float*)d_in[12];
  const float* zb1 = (const float*)d_in[13];
  const float* zW2 = (const float*)d_in[14];
  const float* zb2 = (const float*)d_in[15];
  const float* zW3 = (const float*)d_in[16];
  const float* zb3 = (const float*)d_in[17];
  const float* yW1 = (const float*)d_in[18];
  const float* yb1 = (const float*)d_in[19];
  const float* yW2 = (const float*)d_in[20];
  const float* yb2 = (const float*)d_in[21];
  const float* yW3 = (const float*)d_in[22];
  const float* yb3 = (const float*)d_in[23];
  float* out = (float*)d_out;
  unsigned int* ws = (unsigned int*)d_ws;

  (void)hipMemsetAsync(out, 0, 2 * sizeof(float), stream);

  prep_kernel<<<kNFrag + 1, 64, 0, stream>>>(
      A, Bm, Cm, Dm,
      pW1, pb1, pW2, pb2, pW3, pb3,
      zW1, zb1, zW2, zb2, zW3, zb3,
      yW1, yb1, yW2, yb2, yW3, yb3, ws);

  bsde_kernel<<<kB / 16, 128, 0, stream>>>(dw, X0, ws, out);
}